// Round 5
// baseline (106.183 us; speedup 1.0000x reference)
//
#include <hip/hip_runtime.h>
#include <math.h>

// QRNN: B=8, T=4096, C=256, UNITS=256, WINDOW=2
// gates = concat(x[t-1],x[t]) @ K[512,768] + bias ; z=tanh f=sig o=sig
// c_t = f*c_{t-1} + (1-f)*z_t ; h = sig(o)*c
// GEMM M=32768 K=512 N=768, fp16 MFMA single pass.
// A via LDS dbuf (gload_lds, swizzled); B direct global->reg frags (L2-resident,
// 1-step prefetch). g = 1-f stored fp16. All gates via LDS-transpose epilogue.

#define Bq 8
#define Tq 4096
#define NCq 64
#define Lq 64

typedef __attribute__((ext_vector_type(8))) _Float16 f16x8;
typedef __attribute__((ext_vector_type(4))) float f32x4;

__device__ __forceinline__ float sigmoidf_(float x) {
    return 1.f / (1.f + __expf(-x));
}
__device__ __forceinline__ float tanh_fast(float x) {
    return 1.f - 2.f / (__expf(2.f * x) + 1.f);
}
__device__ __forceinline__ unsigned short f16b(float a) {
    _Float16 h = (_Float16)a;
    return *(unsigned short*)&h;
}
__device__ __forceinline__ void gload16(const void* g, void* l) {
    __builtin_amdgcn_global_load_lds(
        (const __attribute__((address_space(1))) void*)g,
        (__attribute__((address_space(3))) void*)l, 16, 0, 0);
}

// ---------- prep 1: x -> padded fp16 (xp[b][tp][c], tp=t+1, row 0 = zeros)
__global__ __launch_bounds__(256) void split_x(
    const float* __restrict__ x, _Float16* __restrict__ xh)
{
    int idx = blockIdx.x * 256 + threadIdx.x;
    if (idx >= Bq * 4097 * 64) return;
    int b  = idx / (4097 * 64);
    int r  = idx % (4097 * 64);
    int tp = r / 64, c4 = (r % 64) << 2;
    size_t o = ((size_t)(b * 4097 + tp) << 8) + c4;
    _Float16 h4[4] = {(_Float16)0.f, (_Float16)0.f, (_Float16)0.f, (_Float16)0.f};
    if (tp > 0) {
        const float4 v = *(const float4*)&x[((size_t)(b * 4096 + tp - 1) << 8) + c4];
        h4[0] = (_Float16)v.x; h4[1] = (_Float16)v.y;
        h4[2] = (_Float16)v.z; h4[3] = (_Float16)v.w;
    }
    *(ushort4*)&xh[o] = *(ushort4*)h4;
}

// ---------- prep 2: kernel [512][768] -> transposed fp16 [768][512]
__global__ __launch_bounds__(256) void split_k(
    const float* __restrict__ kw, _Float16* __restrict__ bh)
{
    int idx = blockIdx.x * 256 + threadIdx.x;
    if (idx >= 768 * 512) return;
    int n = idx >> 9, k = idx & 511;
    bh[((size_t)n << 9) + k] = (_Float16)kw[(size_t)k * 768 + n];
}

// ---------- main GEMM: 128x128 tile, BK=32, 4 waves (2x2), 16x16x32 f16 MFMA
__global__ __launch_bounds__(256) void conv_gemm(
    const _Float16* __restrict__ xh, const _Float16* __restrict__ bth,
    const float* __restrict__ bias,
    _Float16* __restrict__ Z, _Float16* __restrict__ G, _Float16* __restrict__ SO)
{
    __shared__ __align__(16) char smem[32768];   // loop: A dbuf 16KB; epi: 32KB
    const int tid = threadIdx.x;
    const int l = tid & 63, w = tid >> 6;
    const int wr = w >> 1, wc = w & 1;
    const int bm = blockIdx.x;            // 0..255
    const int b  = bm >> 5;
    const int t0 = (bm & 31) << 7;
    const int n0 = blockIdx.y << 7;       // 0..640

    f32x4 acc[4][4] = {};

    // A staging: LDS linear dest; source pre-swizzled so LDS(row, slot) holds
    // k-group (slot ^ ((row>>1)&3))
    const int rowT   = tid >> 2;
    const int slotSw = (tid & 3) ^ ((rowT >> 1) & 3);
    size_t gaBase = ((size_t)(b * 4097 + t0 + rowT) << 8) + (slotSw << 3);
    const int ldsW = w << 9;   // halves: wave base (w*1024 bytes)

    int offA[4];
    const int colB = (l >> 4) << 4;
    #pragma unroll
    for (int i = 0; i < 4; ++i) {
        int ra = wr * 64 + i * 16 + (l & 15);
        offA[i] = ((ra << 6) + colB) ^ (((ra >> 1) & 3) << 4);
    }
    // B frag global bases (unswizzled; contiguous 16B per lane)
    size_t bB[4];
    #pragma unroll
    for (int ni = 0; ni < 4; ++ni)
        bB[ni] = ((size_t)(n0 + wc * 64 + ni * 16 + (l & 15)) << 9) + ((l >> 4) << 3);

    auto stageA = [&](int buf, int kk) {
        size_t ga = gaBase + (size_t)kk * 32;
        _Float16* pA = (_Float16*)smem + buf * 4096 + ldsW;
        gload16(xh + ga,         pA);
        gload16(xh + ga + 16384, pA + 2048);   // rows +64 (A row = 256 halves)
    };
    auto loadB = [&](int kk, f16x8* fb) {
        #pragma unroll
        for (int ni = 0; ni < 4; ++ni)
            fb[ni] = *(const f16x8*)(bth + bB[ni] + (size_t)kk * 32);
    };
    auto computeA = [&](int buf, const f16x8* fb) {
        const char* bA = (const char*)smem + buf * 8192;
        f16x8 fa[4];
        #pragma unroll
        for (int i = 0; i < 4; ++i)
            fa[i] = *(const f16x8*)(bA + offA[i]);
        #pragma unroll
        for (int mi = 0; mi < 4; ++mi)
            #pragma unroll
            for (int ni = 0; ni < 4; ++ni)
                acc[mi][ni] = __builtin_amdgcn_mfma_f32_16x16x32_f16(
                    fa[mi], fb[ni], acc[mi][ni], 0, 0, 0);
    };

    f16x8 fbA[4], fbB[4];
    stageA(0, 0);
    loadB(0, fbA);
    __syncthreads();
    #pragma unroll
    for (int kp = 0; kp < 8; ++kp) {
        const int k0 = kp * 2;
        if (k0 + 1 < 16) { stageA(1, k0 + 1); loadB(k0 + 1, fbB); }
        computeA(0, fbA);
        if (k0 + 1 < 16) __syncthreads();
        if (k0 + 1 < 16) {
            if (k0 + 2 < 16) { stageA(0, k0 + 2); loadB(k0 + 2, fbA); }
            computeA(1, fbB);
            if (k0 + 2 < 16) __syncthreads();
        }
    }
    __syncthreads();              // before reusing LDS for epilogue

    // ---- epilogue: bias + activation, LDS transpose, coalesced fp16 stores ----
    const int gsel = (int)(blockIdx.y >> 1);   // 0:z 1:f(store g=1-f) 2:o
    float bb[4];
    #pragma unroll
    for (int ni = 0; ni < 4; ++ni)
        bb[ni] = bias[n0 + wc * 64 + ni * 16 + (l & 15)];

    unsigned short* Hd = (unsigned short*)smem;   // 32KB 128x128 fp16 tile
    #pragma unroll
    for (int ni = 0; ni < 4; ++ni) {
        const int cl = wc * 64 + ni * 16 + (l & 15);
        #pragma unroll
        for (int mi = 0; mi < 4; ++mi)
            #pragma unroll
            for (int r = 0; r < 4; ++r) {
                const int trl = wr * 64 + mi * 16 + ((l >> 4) << 2) + r;
                float g = acc[mi][ni][r] + bb[ni];
                float a = (gsel == 0) ? tanh_fast(g)
                        : (gsel == 1) ? sigmoidf_(-g)   // g = 1 - f
                                      : sigmoidf_(g);
                int byt = (trl << 8) + ((cl << 1) ^ (((trl >> 2) & 3) << 4));
                *(unsigned short*)((char*)Hd + byt) = f16b(a);
            }
    }
    __syncthreads();
    _Float16* Gg = (gsel == 0) ? Z : (gsel == 1) ? G : SO;
    const int u0 = n0 & 255;
    const size_t gbase = ((size_t)(b * 4096 + t0) << 8) + u0;  // halves
    #pragma unroll
    for (int j = 0; j < 8; ++j) {
        int hoff = tid * 8 + j * 2048;         // halves
        int row  = hoff >> 7;
        int cby  = (hoff & 127) << 1;          // bytes within row
        int srcB = (row << 8) + (cby ^ (((row >> 2) & 3) << 4));
        int4 v = *(const int4*)((const char*)Hd + srcB);
        *(int4*)&Gg[gbase + ((size_t)row << 8) + (cby >> 1)] = v;
    }
}

// ---------- scan kernels
__global__ __launch_bounds__(256) void chunk_reduce(
    const _Float16* __restrict__ Z, const _Float16* __restrict__ G,
    float* __restrict__ CA, float* __restrict__ CB)
{
    const int u = threadIdx.x;
    const int blk = blockIdx.x;
    const int b = blk >> 6, ck = blk & 63;
    size_t base = (((size_t)b << 12) + ck * Lq) * 256 + u;
    float A = 1.f, Bv = 0.f;
    #pragma unroll 8
    for (int s = 0; s < Lq; ++s) {
        size_t idx = base + (size_t)s * 256;
        float g = (float)G[idx];
        float z = (float)Z[idx];
        Bv = fmaf(1.f - g, Bv, g * z);
        A *= (1.f - g);
    }
    size_t cidx = ((size_t)b * NCq + ck) * 256 + u;
    CA[cidx] = A;
    CB[cidx] = Bv;
}

__global__ __launch_bounds__(256) void carry_scan(
    const float* __restrict__ CA, const float* __restrict__ CB,
    float* __restrict__ CIN)
{
    const int u = threadIdx.x;
    const int b = blockIdx.x;
    float c = 0.f;
    #pragma unroll 8
    for (int k = 0; k < NCq; ++k) {
        size_t idx = ((size_t)b * NCq + k) * 256 + u;
        CIN[idx] = c;
        c = fmaf(CA[idx], c, CB[idx]);
    }
}

__global__ __launch_bounds__(256) void apply_scan(
    const _Float16* __restrict__ Z, const _Float16* __restrict__ G,
    const _Float16* __restrict__ SO, const float* __restrict__ CIN,
    float* __restrict__ out)
{
    const int u = threadIdx.x;
    const int blk = blockIdx.x;
    const int b = blk >> 6, ck = blk & 63;
    float c = CIN[((size_t)b * NCq + ck) * 256 + u];
    size_t base = (((size_t)b << 12) + ck * Lq) * 256 + u;
    #pragma unroll 8
    for (int s = 0; s < Lq; ++s) {
        size_t idx = base + (size_t)s * 256;
        float g = (float)G[idx], z = (float)Z[idx];
        c = fmaf(1.f - g, c, g * z);
        out[idx] = (float)SO[idx] * c;
    }
}

extern "C" void kernel_launch(void* const* d_in, const int* in_sizes, int n_in,
                              void* d_out, int out_size, void* d_ws, size_t ws_size,
                              hipStream_t stream) {
    const float* x    = (const float*)d_in[0];
    const float* kw   = (const float*)d_in[1];
    const float* bias = (const float*)d_in[2];
    float* out = (float*)d_out;

    char* p = (char*)d_ws;
    _Float16* xh  = (_Float16*)p; p += (size_t)Bq * 4097 * 256 * 2;
    _Float16* bth = (_Float16*)p; p += (size_t)768 * 512 * 2;
    _Float16* Z   = (_Float16*)p; p += (size_t)Bq * Tq * 256 * 2;
    _Float16* G   = (_Float16*)p; p += (size_t)Bq * Tq * 256 * 2;
    _Float16* SO  = (_Float16*)p; p += (size_t)Bq * Tq * 256 * 2;
    float* CA  = (float*)p; p += (size_t)Bq * NCq * 256 * 4;
    float* CB  = (float*)p; p += (size_t)Bq * NCq * 256 * 4;
    float* CIN = (float*)p;

    split_x<<<(Bq * 4097 * 64 + 255) / 256, 256, 0, stream>>>(x, xh);
    split_k<<<(768 * 512 + 255) / 256, 256, 0, stream>>>(kw, bth);
    dim3 g1(256, 6);
    conv_gemm<<<g1, 256, 0, stream>>>(xh, bth, bias, Z, G, SO);
    chunk_reduce<<<512, 256, 0, stream>>>(Z, G, CA, CB);
    carry_scan<<<Bq, 256, 0, stream>>>(CA, CB, CIN);
    apply_scan<<<512, 256, 0, stream>>>(Z, G, SO, CIN, out);
}

// Round 6
// 87.028 us; speedup vs baseline: 1.2201x; 1.2201x over previous
//
#include <hip/hip_runtime.h>
#include <math.h>

// QRNN: B=8, T=4096, C=256, UNITS=256, WINDOW=2
// gates = concat(x[t-1],x[t]) @ K[512,768] + bias ; z=tanh f=sig o=sig
// c_t = f*c_{t-1} + (1-f)*z_t ; h = sig(o)*c
// GEMM M=32768 K=512 N=768, fp16 MFMA single pass.
// A,B via LDS (gload_lds, pre-swizzled source), 3-buffer 2-deep prefetch,
// counted vmcnt(8) barriers (loads never drain), setprio around MFMA,
// XCD-swizzled block order. g = 1-f stored fp16. LDS-transpose epilogue.

#define Bq 8
#define Tq 4096
#define NCq 64
#define Lq 64

typedef __attribute__((ext_vector_type(8))) _Float16 f16x8;
typedef __attribute__((ext_vector_type(4))) float f32x4;

__device__ __forceinline__ float sigmoidf_(float x) {
    return 1.f / (1.f + __expf(-x));
}
__device__ __forceinline__ float tanh_fast(float x) {
    return 1.f - 2.f / (__expf(2.f * x) + 1.f);
}
__device__ __forceinline__ unsigned short f16b(float a) {
    _Float16 h = (_Float16)a;
    return *(unsigned short*)&h;
}
__device__ __forceinline__ void gload16(const void* g, void* l) {
    __builtin_amdgcn_global_load_lds(
        (const __attribute__((address_space(1))) void*)g,
        (__attribute__((address_space(3))) void*)l, 16, 0, 0);
}

// ---------- prep 1: x -> padded fp16 (xp[b][tp][c], tp=t+1, row 0 = zeros)
__global__ __launch_bounds__(256) void split_x(
    const float* __restrict__ x, _Float16* __restrict__ xh)
{
    int idx = blockIdx.x * 256 + threadIdx.x;
    if (idx >= Bq * 4097 * 64) return;
    int b  = idx / (4097 * 64);
    int r  = idx % (4097 * 64);
    int tp = r / 64, c4 = (r % 64) << 2;
    size_t o = ((size_t)(b * 4097 + tp) << 8) + c4;
    _Float16 h4[4] = {(_Float16)0.f, (_Float16)0.f, (_Float16)0.f, (_Float16)0.f};
    if (tp > 0) {
        const float4 v = *(const float4*)&x[((size_t)(b * 4096 + tp - 1) << 8) + c4];
        h4[0] = (_Float16)v.x; h4[1] = (_Float16)v.y;
        h4[2] = (_Float16)v.z; h4[3] = (_Float16)v.w;
    }
    *(ushort4*)&xh[o] = *(ushort4*)h4;
}

// ---------- prep 2: kernel [512][768] -> transposed fp16 [768][512]
__global__ __launch_bounds__(256) void split_k(
    const float* __restrict__ kw, _Float16* __restrict__ bh)
{
    int idx = blockIdx.x * 256 + threadIdx.x;
    if (idx >= 768 * 512) return;
    int n = idx >> 9, k = idx & 511;
    bh[((size_t)n << 9) + k] = (_Float16)kw[(size_t)k * 768 + n];
}

// ---------- main GEMM: 128x128 tile, BK=32, 4 waves (2x2), 16x16x32 f16 MFMA
__global__ __launch_bounds__(256) void conv_gemm(
    const _Float16* __restrict__ xh, const _Float16* __restrict__ bth,
    const float* __restrict__ bias,
    _Float16* __restrict__ Z, _Float16* __restrict__ G, _Float16* __restrict__ SO)
{
    __shared__ __align__(16) char smem[49152];   // 3 bufs x (A 8KB + B 8KB)
    const int tid = threadIdx.x;
    const int l = tid & 63, w = tid >> 6;
    const int wr = w >> 1, wc = w & 1;

    // XCD swizzle: cluster same-N-panel blocks per XCD (1536 % 8 == 0)
    const int p  = blockIdx.x + (blockIdx.y << 8);     // 0..1535
    const int Lw = (p & 7) * 192 + (p >> 3);
    const int bm = Lw & 255;
    const int by = Lw >> 8;               // 0..5
    const int b  = bm >> 5;
    const int t0 = (bm & 31) << 7;
    const int n0 = by << 7;

    f32x4 acc[4][4] = {};

    // staging: LDS linear dest; source pre-swizzled so LDS(row, slot) holds
    // k-group (slot ^ ((row>>1)&3))
    const int rowT   = tid >> 2;
    const int slotSw = (tid & 3) ^ ((rowT >> 1) & 3);
    size_t gaBase = ((size_t)(b * 4097 + t0 + rowT) << 8) + (slotSw << 3);
    size_t gbBase = ((size_t)(n0 + rowT) << 9) + (slotSw << 3);
    const int ldsW = w << 9;   // halves: wave base (w*1024 bytes)

    int offA[4], offB[4];
    const int colB = (l >> 4) << 4;
    #pragma unroll
    for (int i = 0; i < 4; ++i) {
        int ra = wr * 64 + i * 16 + (l & 15);
        offA[i] = ((ra << 6) + colB) ^ (((ra >> 1) & 3) << 4);
        int rb = wc * 64 + i * 16 + (l & 15);
        offB[i] = ((rb << 6) + colB) ^ (((rb >> 1) & 3) << 4);
    }

    auto stage = [&](int kk) {
        const int buf = kk % 3;
        _Float16* pA = (_Float16*)(smem + buf * 16384) + ldsW;
        _Float16* pB = (_Float16*)(smem + buf * 16384 + 8192) + ldsW;
        size_t ga = gaBase + (size_t)kk * 32;   // rolls into next t-row for kk>=8
        size_t gb = gbBase + (size_t)kk * 32;
        gload16(xh  + ga,          pA);
        gload16(xh  + ga + 16384,  pA + 2048);   // rows +64 (A row = 256 halves)
        gload16(bth + gb,          pB);
        gload16(bth + gb + 32768,  pB + 2048);   // rows +64 (B row = 512 halves)
    };

    auto compute = [&](int kk) {
        const char* bA = (const char*)smem + (kk % 3) * 16384;
        const char* bB = bA + 8192;
        f16x8 fa[4], fb[4];
        #pragma unroll
        for (int i = 0; i < 4; ++i) {
            fa[i] = *(const f16x8*)(bA + offA[i]);
            fb[i] = *(const f16x8*)(bB + offB[i]);
        }
        __builtin_amdgcn_s_setprio(1);
        #pragma unroll
        for (int mi = 0; mi < 4; ++mi)
            #pragma unroll
            for (int ni = 0; ni < 4; ++ni)
                acc[mi][ni] = __builtin_amdgcn_mfma_f32_16x16x32_f16(
                    fa[mi], fb[ni], acc[mi][ni], 0, 0, 0);
        __builtin_amdgcn_s_setprio(0);
    };

    stage(0);
    stage(1);
    // counted-vmcnt pipeline: 2 stages (8 loads) stay in flight across barriers
#define QSTEP(k, V) \
    if ((k) + 2 < 16) stage((k) + 2); \
    asm volatile("s_waitcnt vmcnt(" #V ")" ::: "memory"); \
    __builtin_amdgcn_s_barrier(); \
    compute(k); \
    asm volatile("s_waitcnt lgkmcnt(0)" ::: "memory"); \
    __builtin_amdgcn_sched_barrier(0); \
    __builtin_amdgcn_s_barrier();
    QSTEP(0, 8)  QSTEP(1, 8)  QSTEP(2, 8)  QSTEP(3, 8)
    QSTEP(4, 8)  QSTEP(5, 8)  QSTEP(6, 8)  QSTEP(7, 8)
    QSTEP(8, 8)  QSTEP(9, 8)  QSTEP(10, 8) QSTEP(11, 8)
    QSTEP(12, 8) QSTEP(13, 8) QSTEP(14, 4) QSTEP(15, 0)
#undef QSTEP

    // ---- epilogue: bias + activation, LDS transpose, coalesced fp16 stores ----
    const int gsel = by >> 1;   // 0:z 1:f(store g=1-f) 2:o
    float bb[4];
    #pragma unroll
    for (int ni = 0; ni < 4; ++ni)
        bb[ni] = bias[n0 + wc * 64 + ni * 16 + (l & 15)];

    unsigned short* Hd = (unsigned short*)smem;   // 32KB 128x128 fp16 tile
    #pragma unroll
    for (int ni = 0; ni < 4; ++ni) {
        const int cl = wc * 64 + ni * 16 + (l & 15);
        #pragma unroll
        for (int mi = 0; mi < 4; ++mi)
            #pragma unroll
            for (int r = 0; r < 4; ++r) {
                const int trl = wr * 64 + mi * 16 + ((l >> 4) << 2) + r;
                float g = acc[mi][ni][r] + bb[ni];
                float a = (gsel == 0) ? tanh_fast(g)
                        : (gsel == 1) ? sigmoidf_(-g)   // g = 1 - f
                                      : sigmoidf_(g);
                int byt = (trl << 8) + ((cl << 1) ^ (((trl >> 2) & 3) << 4));
                *(unsigned short*)((char*)Hd + byt) = f16b(a);
            }
    }
    __syncthreads();
    _Float16* Gg = (gsel == 0) ? Z : (gsel == 1) ? G : SO;
    const int u0 = n0 & 255;
    const size_t gbase = ((size_t)(b * 4096 + t0) << 8) + u0;  // halves
    #pragma unroll
    for (int j = 0; j < 8; ++j) {
        int hoff = tid * 8 + j * 2048;         // halves
        int row  = hoff >> 7;
        int cby  = (hoff & 127) << 1;          // bytes within row
        int srcB = (row << 8) + (cby ^ (((row >> 2) & 3) << 4));
        int4 v = *(const int4*)((const char*)Hd + srcB);
        *(int4*)&Gg[gbase + ((size_t)row << 8) + (cby >> 1)] = v;
    }
}

// ---------- scan kernels
__global__ __launch_bounds__(256) void chunk_reduce(
    const _Float16* __restrict__ Z, const _Float16* __restrict__ G,
    float* __restrict__ CA, float* __restrict__ CB)
{
    const int u = threadIdx.x;
    const int blk = blockIdx.x;
    const int b = blk >> 6, ck = blk & 63;
    size_t base = (((size_t)b << 12) + ck * Lq) * 256 + u;
    float A = 1.f, Bv = 0.f;
    #pragma unroll 8
    for (int s = 0; s < Lq; ++s) {
        size_t idx = base + (size_t)s * 256;
        float g = (float)G[idx];
        float z = (float)Z[idx];
        Bv = fmaf(1.f - g, Bv, g * z);
        A *= (1.f - g);
    }
    size_t cidx = ((size_t)b * NCq + ck) * 256 + u;
    CA[cidx] = A;
    CB[cidx] = Bv;
}

__global__ __launch_bounds__(256) void carry_scan(
    const float* __restrict__ CA, const float* __restrict__ CB,
    float* __restrict__ CIN)
{
    const int u = threadIdx.x;
    const int b = blockIdx.x;
    float c = 0.f;
    #pragma unroll 8
    for (int k = 0; k < NCq; ++k) {
        size_t idx = ((size_t)b * NCq + k) * 256 + u;
        CIN[idx] = c;
        c = fmaf(CA[idx], c, CB[idx]);
    }
}

__global__ __launch_bounds__(256) void apply_scan(
    const _Float16* __restrict__ Z, const _Float16* __restrict__ G,
    const _Float16* __restrict__ SO, const float* __restrict__ CIN,
    float* __restrict__ out)
{
    const int u = threadIdx.x;
    const int blk = blockIdx.x;
    const int b = blk >> 6, ck = blk & 63;
    float c = CIN[((size_t)b * NCq + ck) * 256 + u];
    size_t base = (((size_t)b << 12) + ck * Lq) * 256 + u;
    #pragma unroll 8
    for (int s = 0; s < Lq; ++s) {
        size_t idx = base + (size_t)s * 256;
        float g = (float)G[idx], z = (float)Z[idx];
        c = fmaf(1.f - g, c, g * z);
        out[idx] = (float)SO[idx] * c;
    }
}

extern "C" void kernel_launch(void* const* d_in, const int* in_sizes, int n_in,
                              void* d_out, int out_size, void* d_ws, size_t ws_size,
                              hipStream_t stream) {
    const float* x    = (const float*)d_in[0];
    const float* kw   = (const float*)d_in[1];
    const float* bias = (const float*)d_in[2];
    float* out = (float*)d_out;

    char* p = (char*)d_ws;
    _Float16* xh  = (_Float16*)p; p += (size_t)Bq * 4097 * 256 * 2;
    _Float16* bth = (_Float16*)p; p += (size_t)768 * 512 * 2;
    _Float16* Z   = (_Float16*)p; p += (size_t)Bq * Tq * 256 * 2;
    _Float16* G   = (_Float16*)p; p += (size_t)Bq * Tq * 256 * 2;
    _Float16* SO  = (_Float16*)p; p += (size_t)Bq * Tq * 256 * 2;
    float* CA  = (float*)p; p += (size_t)Bq * NCq * 256 * 4;
    float* CB  = (float*)p; p += (size_t)Bq * NCq * 256 * 4;
    float* CIN = (float*)p;

    split_x<<<(Bq * 4097 * 64 + 255) / 256, 256, 0, stream>>>(x, xh);
    split_k<<<(768 * 512 + 255) / 256, 256, 0, stream>>>(kw, bth);
    dim3 g1(256, 6);
    conv_gemm<<<g1, 256, 0, stream>>>(xh, bth, bias, Z, G, SO);
    chunk_reduce<<<512, 256, 0, stream>>>(Z, G, CA, CB);
    carry_scan<<<Bq, 256, 0, stream>>>(CA, CB, CIN);
    apply_scan<<<512, 256, 0, stream>>>(Z, G, SO, CIN, out);
}